// Round 12
// baseline (29.597 us; speedup 1.0000x reference)
//
#include <hip/hip_runtime.h>

#define H 512
#define W 512

typedef float f32x4 __attribute__((ext_vector_type(4)));

// DPP wave rotates: *_ror moves data toward HIGHER lanes (dst[i]=src[i-1]).
__device__ __forceinline__ float dpp_left1(float v) {   // dst[i] = src[(i-1) & 63]
    return __int_as_float(__builtin_amdgcn_update_dpp(
        0, __float_as_int(v), 0x13C /*wave_ror:1*/, 0xF, 0xF, false));
}
__device__ __forceinline__ float dpp_right1(float v) {  // dst[i] = src[(i+1) & 63]
    return __int_as_float(__builtin_amdgcn_update_dpp(
        0, __float_as_int(v), 0x134 /*wave_rol:1*/, 0xF, 0xF, false));
}

// Exact R6 structure (4 output rows/wave, scalar math, DPP halo, NT stores,
// keep[3] subtract rows) with ONE change: tail loads triple-buffered 2-ahead
// so each wave holds ~3KB (not 1KB) of reads in flight through the tail phase.
__global__ __launch_bounds__(256, 4) void lvar_kernel(const float* __restrict__ x,
                                                      float* __restrict__ out) {
    const int lane = threadIdx.x;                 // 0..63, owns cols 8*lane..8*lane+7
    const int wv   = threadIdx.y;                 // 0..3
    const int bid  = blockIdx.x;
    const int wg   = (bid & 7) * 192 + (bid >> 3);// XCD-bijective (1536 % 8 == 0)
    const int img  = wg >> 5;                     // 0..47
    const int band = wg & 31;
    const int R    = band * 16 + wv * 4;          // this wave's first output row

    const float* __restrict__ xim = x + (size_t)img * (H * W);
    float* __restrict__ oim = out + (size_t)img * (H * W);
    const int c8 = lane * 8;
    const float inv = 1.0f / 49.0f;

    float s[8], q[8];        // running 7-row vertical sums of x, x^2
    float keep[3][8];        // rows R-3..R-1, subtracted at steps 1..3

    #pragma unroll
    for (int c = 0; c < 8; ++c) { s[c] = 0.f; q[c] = 0.f; }

    auto loadrow = [&](int r, float v[8]) {
        const int gr = r & (H - 1);
        const f32x4* p = (const f32x4*)(xim + gr * W + c8);
        const f32x4 a = p[0], b = p[1];
        v[0]=a.x; v[1]=a.y; v[2]=a.z; v[3]=a.w;
        v[4]=b.x; v[5]=b.y; v[6]=b.z; v[7]=b.w;
    };

    auto emit = [&](int r) {
        float Wn[14], W2[14];
        #pragma unroll
        for (int t = 0; t < 3; ++t) {             // circular col halo via DPP
            Wn[t]      = dpp_left1(s[5 + t]);     // left neighbor's cols 5..7
            W2[t]      = dpp_left1(q[5 + t]);
            Wn[11 + t] = dpp_right1(s[t]);        // right neighbor's cols 0..2
            W2[11 + t] = dpp_right1(q[t]);
        }
        #pragma unroll
        for (int c = 0; c < 8; ++c) { Wn[3 + c] = s[c]; W2[3 + c] = q[c]; }

        float res[8];
        float hs = Wn[0]+Wn[1]+Wn[2]+Wn[3]+Wn[4]+Wn[5]+Wn[6];
        float hq = W2[0]+W2[1]+W2[2]+W2[3]+W2[4]+W2[5]+W2[6];
        { const float m = hs * inv; res[0] = fmaf(-m, m, hq * inv); }
        #pragma unroll
        for (int k = 1; k < 8; ++k) {
            hs += Wn[k + 6] - Wn[k - 1];
            hq += W2[k + 6] - W2[k - 1];
            const float m = hs * inv;
            res[k] = fmaf(-m, m, hq * inv);
        }
        f32x4* qp = (f32x4*)(oim + r * W + c8);
        f32x4 o0 = {res[0], res[1], res[2], res[3]};
        f32x4 o1 = {res[4], res[5], res[6], res[7]};
        __builtin_nontemporal_store(o0, qp);      // write-once output
        __builtin_nontemporal_store(o1, qp + 1);
    };

    auto update = [&](const float nv[8], const float old[8]) {
        #pragma unroll
        for (int c = 0; c < 8; ++c) {
            s[c] += nv[c] - old[c];
            q[c] = fmaf(nv[c], nv[c], q[c]);
            q[c] = fmaf(-old[c], old[c], q[c]);
        }
    };

    // ---- init: rows R-3 .. R+3 (keep first 3 for subtraction) ----
    #pragma unroll
    for (int k = 0; k < 3; ++k) {
        loadrow(R - 3 + k, keep[k]);
        #pragma unroll
        for (int c = 0; c < 8; ++c) {
            s[c] += keep[k][c];
            q[c] = fmaf(keep[k][c], keep[k][c], q[c]);
        }
    }
    {
        float t[8];
        #pragma unroll
        for (int k = 3; k < 7; ++k) {
            loadrow(R - 3 + k, t);
            #pragma unroll
            for (int c = 0; c < 8; ++c) {
                s[c] += t[c];
                q[c] = fmaf(t[c], t[c], q[c]);
            }
        }
    }

    // ---- 4 output rows; tail loads triple-buffered, 2-ahead ----
    float va[8], vb[8], vc[8];
    loadrow(R + 4, va);
    loadrow(R + 5, vb);
    emit(R);
    loadrow(R + 6, vc);
    update(va, keep[0]); emit(R + 1);
    update(vb, keep[1]); emit(R + 2);
    update(vc, keep[2]); emit(R + 3);
}

extern "C" void kernel_launch(void* const* d_in, const int* in_sizes, int n_in,
                              void* d_out, int out_size, void* d_ws, size_t ws_size,
                              hipStream_t stream) {
    const float* x = (const float*)d_in[0];
    float* out = (float*)d_out;
    const int nimg = in_sizes[0] / (H * W);       // 48
    dim3 grid(nimg * 32);                         // 1536 blocks (8 | 1536)
    dim3 block(64, 4);
    lvar_kernel<<<grid, block, 0, stream>>>(x, out);
}

// Round 13
// 21.835 us; speedup vs baseline: 1.3555x; 1.3555x over previous
//
#include <hip/hip_runtime.h>

#define H 512
#define W 512

typedef float f32x4 __attribute__((ext_vector_type(4)));

// DPP wave rotates: *_ror moves data toward HIGHER lanes (dst[i]=src[i-1]).
__device__ __forceinline__ float dpp_left1(float v) {   // dst[i] = src[(i-1) & 63]
    return __int_as_float(__builtin_amdgcn_update_dpp(
        0, __float_as_int(v), 0x13C /*wave_ror:1*/, 0xF, 0xF, false));
}
__device__ __forceinline__ float dpp_right1(float v) {  // dst[i] = src[(i+1) & 63]
    return __int_as_float(__builtin_amdgcn_update_dpp(
        0, __float_as_int(v), 0x134 /*wave_rol:1*/, 0xF, 0xF, false));
}

// 2 output rows per wave: ALL 8 input rows issued as one upfront burst,
// zero tail loads -> every wave spends its whole life in the deep-MLP phase.
// 12288 waves (2x R6) keep the HBM pipe saturated by wave churn.
__global__ __launch_bounds__(256, 4) void lvar_kernel(const float* __restrict__ x,
                                                      float* __restrict__ out) {
    const int lane = threadIdx.x;                 // 0..63, owns cols 8*lane..8*lane+7
    const int wv   = threadIdx.y;                 // 0..3
    const int bid  = blockIdx.x;
    const int wg   = (bid & 7) * 384 + (bid >> 3);// XCD-bijective (3072 % 8 == 0)
    const int img  = wg >> 6;                     // 0..47
    const int band = wg & 63;                     // 8-row band
    const int R    = band * 8 + wv * 2;           // this wave's first output row

    const float* __restrict__ xim = x + (size_t)img * (H * W);
    float* __restrict__ oim = out + (size_t)img * (H * W);
    const int c8 = lane * 8;
    const float inv = 1.0f / 49.0f;

    auto loadrow = [&](int r, float v[8]) {
        const int gr = r & (H - 1);
        const f32x4* p = (const f32x4*)(xim + gr * W + c8);
        const f32x4 a = p[0], b = p[1];
        v[0]=a.x; v[1]=a.y; v[2]=a.z; v[3]=a.w;
        v[4]=b.x; v[5]=b.y; v[6]=b.z; v[7]=b.w;
    };

    // ---- burst: all 8 rows (R-3 .. R+4) issued before any consumption ----
    float r0[8], r1[8], r2[8], r3[8], r4[8], r5[8], r6[8], r7[8];
    loadrow(R - 3, r0); loadrow(R - 2, r1); loadrow(R - 1, r2); loadrow(R + 0, r3);
    loadrow(R + 1, r4); loadrow(R + 2, r5); loadrow(R + 3, r6); loadrow(R + 4, r7);

    float s[8], q[8];
    #pragma unroll
    for (int c = 0; c < 8; ++c) { s[c] = 0.f; q[c] = 0.f; }

    auto acc = [&](const float v[8]) {
        #pragma unroll
        for (int c = 0; c < 8; ++c) {
            s[c] += v[c];
            q[c] = fmaf(v[c], v[c], q[c]);
        }
    };

    auto emit = [&](int r) {
        float Wn[14], W2[14];
        #pragma unroll
        for (int t = 0; t < 3; ++t) {             // circular col halo via DPP
            Wn[t]      = dpp_left1(s[5 + t]);     // left neighbor's cols 5..7
            W2[t]      = dpp_left1(q[5 + t]);
            Wn[11 + t] = dpp_right1(s[t]);        // right neighbor's cols 0..2
            W2[11 + t] = dpp_right1(q[t]);
        }
        #pragma unroll
        for (int c = 0; c < 8; ++c) { Wn[3 + c] = s[c]; W2[3 + c] = q[c]; }

        float res[8];
        float hs = Wn[0]+Wn[1]+Wn[2]+Wn[3]+Wn[4]+Wn[5]+Wn[6];
        float hq = W2[0]+W2[1]+W2[2]+W2[3]+W2[4]+W2[5]+W2[6];
        { const float m = hs * inv; res[0] = fmaf(-m, m, hq * inv); }
        #pragma unroll
        for (int k = 1; k < 8; ++k) {
            hs += Wn[k + 6] - Wn[k - 1];
            hq += W2[k + 6] - W2[k - 1];
            const float m = hs * inv;
            res[k] = fmaf(-m, m, hq * inv);
        }
        f32x4* qp = (f32x4*)(oim + r * W + c8);
        f32x4 o0 = {res[0], res[1], res[2], res[3]};
        f32x4 o1 = {res[4], res[5], res[6], res[7]};
        __builtin_nontemporal_store(o0, qp);      // write-once output
        __builtin_nontemporal_store(o1, qp + 1);
    };

    // ---- consume in load order; rows r1..r6 die at their acc ----
    acc(r0); acc(r1); acc(r2); acc(r3); acc(r4); acc(r5); acc(r6);
    emit(R);
    #pragma unroll
    for (int c = 0; c < 8; ++c) {                 // slide: +row R+4, -row R-3
        s[c] += r7[c] - r0[c];
        q[c] = fmaf(r7[c], r7[c], q[c]);
        q[c] = fmaf(-r0[c], r0[c], q[c]);
    }
    emit(R + 1);
}

extern "C" void kernel_launch(void* const* d_in, const int* in_sizes, int n_in,
                              void* d_out, int out_size, void* d_ws, size_t ws_size,
                              hipStream_t stream) {
    const float* x = (const float*)d_in[0];
    float* out = (float*)d_out;
    const int nimg = in_sizes[0] / (H * W);       // 48
    dim3 grid(nimg * 64);                         // 3072 blocks (8 | 3072)
    dim3 block(64, 4);
    lvar_kernel<<<grid, block, 0, stream>>>(x, out);
}

// Round 14
// 20.943 us; speedup vs baseline: 1.4132x; 1.0426x over previous
//
#include <hip/hip_runtime.h>

#define H 512
#define W 512

typedef float f32x4 __attribute__((ext_vector_type(4)));

// DPP wave rotates: *_ror moves data toward HIGHER lanes (dst[i]=src[i-1]).
__device__ __forceinline__ float dpp_ror1(float v) {   // dst[i] = src[(i-1) & 63]
    return __int_as_float(__builtin_amdgcn_update_dpp(
        0, __float_as_int(v), 0x13C /*wave_ror:1*/, 0xF, 0xF, false));
}
__device__ __forceinline__ float dpp_rol1(float v) {   // dst[i] = src[(i+1) & 63]
    return __int_as_float(__builtin_amdgcn_update_dpp(
        0, __float_as_int(v), 0x134 /*wave_rol:1*/, 0xF, 0xF, false));
}

// R12 structure (2 output rows/wave, 8-row upfront burst) with DENSE memory
// instructions: lane L owns chunkA = cols [4L,4L+4) and chunkB = [256+4L,+4).
// Every load/store is a wave-wide contiguous 1KB float4 access (16 fully-used
// cache lines/instr instead of 32 half-used). Circular chunk order
// A0..A63 B0..B63 keeps the halo on lane+-1 DPP; lanes 0/63 cross the A/B
// boundary via one cndmask per halo value.
__global__ __launch_bounds__(256, 4) void lvar_kernel(const float* __restrict__ x,
                                                      float* __restrict__ out) {
    const int lane = threadIdx.x;                 // 0..63
    const int wv   = threadIdx.y;                 // 0..3
    const int bid  = blockIdx.x;
    const int wg   = (bid & 7) * 384 + (bid >> 3);// XCD-bijective (3072 % 8 == 0)
    const int img  = wg >> 6;                     // 0..47
    const int band = wg & 63;                     // 8-row band
    const int R    = band * 8 + wv * 2;           // this wave's first output row

    const float* __restrict__ xim = x + (size_t)img * (H * W);
    float* __restrict__ oim = out + (size_t)img * (H * W);
    const int c4 = lane * 4;
    const bool is0  = (lane == 0);
    const bool is63 = (lane == 63);
    const float inv = 1.0f / 49.0f;

    auto loadrow = [&](int r, float v[8]) {       // v[0..3]=chunkA, v[4..7]=chunkB
        const int gr = r & (H - 1);
        const float* rowp = xim + gr * W;
        const f32x4 a = *(const f32x4*)(rowp + c4);         // dense 1KB wave access
        const f32x4 b = *(const f32x4*)(rowp + 256 + c4);   // dense 1KB wave access
        v[0]=a.x; v[1]=a.y; v[2]=a.z; v[3]=a.w;
        v[4]=b.x; v[5]=b.y; v[6]=b.z; v[7]=b.w;
    };

    // ---- burst: all 8 rows (R-3 .. R+4) issued before any consumption ----
    float r0[8], r1[8], r2[8], r3[8], r4[8], r5[8], r6[8], r7[8];
    loadrow(R - 3, r0); loadrow(R - 2, r1); loadrow(R - 1, r2); loadrow(R + 0, r3);
    loadrow(R + 1, r4); loadrow(R + 2, r5); loadrow(R + 3, r6); loadrow(R + 4, r7);

    float s[8], q[8];
    #pragma unroll
    for (int c = 0; c < 8; ++c) { s[c] = 0.f; q[c] = 0.f; }

    auto acc = [&](const float v[8]) {
        #pragma unroll
        for (int c = 0; c < 8; ++c) {
            s[c] += v[c];
            q[c] = fmaf(v[c], v[c], q[c]);
        }
    };

    auto emit = [&](int r) {
        // 10-wide windows per chunk: [pred(3) | own(4) | succ(3)]
        float WA[10], QA[10], WB[10], QB[10];
        #pragma unroll
        for (int j = 1; j <= 3; ++j) {            // predecessors (cols j of pred chunk)
            const float rAs = dpp_ror1(s[j]),     rBs = dpp_ror1(s[4 + j]);
            const float rAq = dpp_ror1(q[j]),     rBq = dpp_ror1(q[4 + j]);
            WA[j - 1] = is0 ? rBs : rAs;          // pred(A_0) = B_63
            WB[j - 1] = is0 ? rAs : rBs;          // pred(B_0) = A_63
            QA[j - 1] = is0 ? rBq : rAq;
            QB[j - 1] = is0 ? rAq : rBq;
        }
        #pragma unroll
        for (int j = 0; j < 4; ++j) {
            WA[3 + j] = s[j];     QA[3 + j] = q[j];
            WB[3 + j] = s[4 + j]; QB[3 + j] = q[4 + j];
        }
        #pragma unroll
        for (int j = 0; j <= 2; ++j) {            // successors (cols j of succ chunk)
            const float rAs = dpp_rol1(s[j]),     rBs = dpp_rol1(s[4 + j]);
            const float rAq = dpp_rol1(q[j]),     rBq = dpp_rol1(q[4 + j]);
            WA[7 + j] = is63 ? rBs : rAs;         // succ(A_63) = B_0
            WB[7 + j] = is63 ? rAs : rBs;         // succ(B_63) = A_0 (wraps mod 512)
            QA[7 + j] = is63 ? rBq : rAq;
            QB[7 + j] = is63 ? rAq : rBq;
        }

        float res[8];
        {   // chunkA outputs (cols 4L .. 4L+3)
            float hs = WA[0]+WA[1]+WA[2]+WA[3]+WA[4]+WA[5]+WA[6];
            float hq = QA[0]+QA[1]+QA[2]+QA[3]+QA[4]+QA[5]+QA[6];
            { const float m = hs * inv; res[0] = fmaf(-m, m, hq * inv); }
            #pragma unroll
            for (int k = 1; k < 4; ++k) {
                hs += WA[k + 6] - WA[k - 1];
                hq += QA[k + 6] - QA[k - 1];
                const float m = hs * inv;
                res[k] = fmaf(-m, m, hq * inv);
            }
        }
        {   // chunkB outputs (cols 256+4L .. 256+4L+3)
            float hs = WB[0]+WB[1]+WB[2]+WB[3]+WB[4]+WB[5]+WB[6];
            float hq = QB[0]+QB[1]+QB[2]+QB[3]+QB[4]+QB[5]+QB[6];
            { const float m = hs * inv; res[4] = fmaf(-m, m, hq * inv); }
            #pragma unroll
            for (int k = 1; k < 4; ++k) {
                hs += WB[k + 6] - WB[k - 1];
                hq += QB[k + 6] - QB[k - 1];
                const float m = hs * inv;
                res[4 + k] = fmaf(-m, m, hq * inv);
            }
        }
        float* rowp = oim + r * W;
        f32x4 oA = {res[0], res[1], res[2], res[3]};
        f32x4 oB = {res[4], res[5], res[6], res[7]};
        __builtin_nontemporal_store(oA, (f32x4*)(rowp + c4));        // dense
        __builtin_nontemporal_store(oB, (f32x4*)(rowp + 256 + c4));  // dense
    };

    // ---- consume in load order ----
    acc(r0); acc(r1); acc(r2); acc(r3); acc(r4); acc(r5); acc(r6);
    emit(R);
    #pragma unroll
    for (int c = 0; c < 8; ++c) {                 // slide: +row R+4, -row R-3
        s[c] += r7[c] - r0[c];
        q[c] = fmaf(r7[c], r7[c], q[c]);
        q[c] = fmaf(-r0[c], r0[c], q[c]);
    }
    emit(R + 1);
}

extern "C" void kernel_launch(void* const* d_in, const int* in_sizes, int n_in,
                              void* d_out, int out_size, void* d_ws, size_t ws_size,
                              hipStream_t stream) {
    const float* x = (const float*)d_in[0];
    float* out = (float*)d_out;
    const int nimg = in_sizes[0] / (H * W);       // 48
    dim3 grid(nimg * 64);                         // 3072 blocks (8 | 3072)
    dim3 block(64, 4);
    lvar_kernel<<<grid, block, 0, stream>>>(x, out);
}